// Round 1
// 903.829 us; speedup vs baseline: 1.2718x; 1.2718x over previous
//
#include <hip/hip_runtime.h>
#include <hip/hip_bf16.h>
#include <math.h>

#define BB 32
#define TT 4096
#define FF 1024
#define DD 1024
#define HH 16
#define DEPTH 64
#define CHUNKS 16
#define TC 256   // t-rows per chunk (TT / CHUNKS)

// ws layout (floats):
// q      [B][D]                  off 0          32768
// c      [B][H]                  off 32768      512
// u      [B][H][F]               off 33280      524288
// mpart  [B][CHUNKS][H]          off 557568     8192
// spart  [B][CHUNKS][H]          off 565760     8192
// wpart  [B][CHUNKS][H][F]       off 573952     8388608
// pooled [B][D]                  off 8962560    32768

// ---------------- Y[b,n] = X[b,:] @ W + bias  (32x1024x1024 GEMM) ----------------
__global__ __launch_bounds__(256) void smallgemm(const float* __restrict__ X,
                                                 const float* __restrict__ W,
                                                 const float* __restrict__ bias,
                                                 float* __restrict__ Y) {
    const int b = blockIdx.y;
    const int n = blockIdx.x * 128 + (threadIdx.x & 31) * 4;
    const int kg = threadIdx.x >> 5;           // 0..7
    const float* __restrict__ x = X + b * DD + kg * 128;
    float4 acc = make_float4(0.f, 0.f, 0.f, 0.f);
#pragma unroll 4
    for (int k = 0; k < 128; ++k) {
        const float s = x[k];
        const float4 wr = *reinterpret_cast<const float4*>(W + (size_t)(kg * 128 + k) * DD + n);
        acc.x = fmaf(s, wr.x, acc.x);
        acc.y = fmaf(s, wr.y, acc.y);
        acc.z = fmaf(s, wr.z, acc.z);
        acc.w = fmaf(s, wr.w, acc.w);
    }
    __shared__ float4 red[8][33];
    red[kg][threadIdx.x & 31] = acc;
    __syncthreads();
    if (threadIdx.x < 32) {
        float4 r = red[0][threadIdx.x];
#pragma unroll
        for (int g = 1; g < 8; ++g) {
            const float4 p = red[g][threadIdx.x];
            r.x += p.x; r.y += p.y; r.z += p.z; r.w += p.w;
        }
        const int nn = blockIdx.x * 128 + threadIdx.x * 4;
        const float4 bb = *reinterpret_cast<const float4*>(bias + nn);
        r.x += bb.x; r.y += bb.y; r.z += bb.z; r.w += bb.w;
        *reinterpret_cast<float4*>(Y + b * DD + nn) = r;
    }
}

// ---------------- c[b,h] = bv_h . q_{b,h} ----------------
__global__ __launch_bounds__(512) void ckern(const float* __restrict__ q,
                                             const float* __restrict__ bv,
                                             float* __restrict__ c) {
    const int tid = threadIdx.x;   // = b*16 + h
    const int b = tid >> 4, h = tid & 15;
    float s = 0.f;
#pragma unroll
    for (int d = 0; d < DEPTH; ++d)
        s = fmaf(bv[h * DEPTH + d], q[b * DD + h * DEPTH + d], s);
    c[tid] = s;
}

// ---------------- u[b,h,f] = sum_d Wv[f, h*64+d] * q[b, h*64+d] ----------------
__global__ __launch_bounds__(256) void ukern(const float* __restrict__ Wv,
                                             const float* __restrict__ q,
                                             float* __restrict__ u) {
    const int h = blockIdx.x;            // 0..15
    const int f0 = blockIdx.y * 64;      // 0,64,...,960
    __shared__ float qs[BB][DEPTH];
    __shared__ float wvs[DEPTH][DEPTH + 1];
    const int tid = threadIdx.x;
#pragma unroll
    for (int i = 0; i < 8; ++i) {
        const int idx = i * 256 + tid;
        const int bq_ = idx >> 6, d = idx & 63;
        qs[bq_][d] = q[bq_ * DD + h * DEPTH + d];
    }
#pragma unroll
    for (int i = 0; i < 16; ++i) {
        const int idx = i * 256 + tid;
        const int r = idx >> 6, d = idx & 63;
        wvs[r][d] = Wv[(size_t)(f0 + r) * DD + h * DEPTH + d];
    }
    __syncthreads();
    const int fl = tid & 63;
    const int bg = (tid >> 6) * 8;
    float acc[8] = {0.f, 0.f, 0.f, 0.f, 0.f, 0.f, 0.f, 0.f};
#pragma unroll 8
    for (int d = 0; d < 64; ++d) {
        const float wv = wvs[fl][d];
#pragma unroll
        for (int j = 0; j < 8; ++j) acc[j] = fmaf(wv, qs[bg + j][d], acc[j]);
    }
#pragma unroll
    for (int j = 0; j < 8; ++j)
        u[((size_t)(bg + j) * HH + h) * FF + f0 + fl] = acc[j];
}

// ---------------- fused: logits + local softmax + partial weighted-sum ----------------
// One block per (b, 256-row t-chunk). Phase 1: logits tile [16h][256t] into LDS
// (logitskern structure). Phase 2: per-h local max/sum, exp in place. Phase 3:
// wpart[h][f] = sum_t p[t][h] * feat[t][f], thread owns f4 = 4*tid (coalesced).
// Writes unnormalized partials + (m,s) per (b,chunk,h); recombined in outkern.
__global__ __launch_bounds__(256) void attnfused(const float* __restrict__ feat,
                                                 const float* __restrict__ u,
                                                 const float* __restrict__ c,
                                                 float* __restrict__ wpart,
                                                 float* __restrict__ mpart,
                                                 float* __restrict__ spart) {
    const int b = blockIdx.y;
    const int chunk = blockIdx.x;
    const int t0 = chunk * TC;
    __shared__ float fs[TC][36];     // pad 36: float4-aligned, conflict-free staging
    __shared__ float us[HH][32];
    __shared__ float ls[TC][20];     // logits -> p; pad 20 keeps float4 alignment
    __shared__ float red[HH][17];
    __shared__ float msh[HH];
    const int tid = threadIdx.x;
    const int tx = tid & 63;
    const int h0 = (tid >> 6) * 4;
    const int r0 = tid >> 3;
    const int f4 = (tid & 7) * 4;

    // ---- phase 1: logits tile ----
    float acc[4][4] = {};
    for (int fc = 0; fc < 32; ++fc) {
        const int f0 = fc * 32;
        __syncthreads();
#pragma unroll
        for (int i = 0; i < 8; ++i) {
            const int row = r0 + i * 32;
            const float4 v = *reinterpret_cast<const float4*>(
                feat + (size_t)(b * TT + t0 + row) * FF + f0 + f4);
            *reinterpret_cast<float4*>(&fs[row][f4]) = v;
        }
        if (tid < 128) {
            const int h = tid >> 3;
            const float4 v = *reinterpret_cast<const float4*>(
                u + (size_t)(b * HH + h) * FF + f0 + f4);
            *reinterpret_cast<float4*>(&us[h][f4]) = v;
        }
        __syncthreads();
#pragma unroll
        for (int g = 0; g < 8; ++g) {
            float4 uu[4];
#pragma unroll
            for (int j = 0; j < 4; ++j)
                uu[j] = *reinterpret_cast<const float4*>(&us[h0 + j][g * 4]);
#pragma unroll
            for (int k = 0; k < 4; ++k) {
                const float4 a = *reinterpret_cast<const float4*>(&fs[tx + k * 64][g * 4]);
#pragma unroll
                for (int j = 0; j < 4; ++j) {
                    acc[k][j] = fmaf(a.x, uu[j].x, acc[k][j]);
                    acc[k][j] = fmaf(a.y, uu[j].y, acc[k][j]);
                    acc[k][j] = fmaf(a.z, uu[j].z, acc[k][j]);
                    acc[k][j] = fmaf(a.w, uu[j].w, acc[k][j]);
                }
            }
        }
    }
    __syncthreads();
#pragma unroll
    for (int j = 0; j < 4; ++j) {
        const float cc = c[b * HH + h0 + j];
#pragma unroll
        for (int k = 0; k < 4; ++k)
            ls[tx + k * 64][h0 + j] = (acc[k][j] + cc) * 0.125f;
    }
    __syncthreads();

    // ---- phase 2: per-h local max, exp, local sum ----
    const int hh = tid >> 4, ii = tid & 15;   // 16 threads per h
    float mx = -1e30f;
#pragma unroll
    for (int k = 0; k < 16; ++k) mx = fmaxf(mx, ls[ii + k * 16][hh]);
    red[hh][ii] = mx;
    __syncthreads();
    if (tid < HH) {
        float m = red[tid][0];
#pragma unroll
        for (int i = 1; i < 16; ++i) m = fmaxf(m, red[tid][i]);
        msh[tid] = m;
    }
    __syncthreads();
    const float m = msh[hh];
    float sm = 0.f;
#pragma unroll
    for (int k = 0; k < 16; ++k) {
        const int t = ii + k * 16;
        const float p = __expf(ls[t][hh] - m);
        ls[t][hh] = p;
        sm += p;
    }
    red[hh][ii] = sm;
    __syncthreads();
    if (tid < HH) {
        float s = 0.f;
#pragma unroll
        for (int i = 0; i < 16; ++i) s += red[tid][i];
        mpart[(b * CHUNKS + chunk) * HH + tid] = msh[tid];
        spart[(b * CHUNKS + chunk) * HH + tid] = s;
    }
    __syncthreads();

    // ---- phase 3: wpart[h][f] = sum_t p[t][h] * feat[t][f] ----
    const int f = tid * 4;
    float4 wacc[16];
#pragma unroll
    for (int h = 0; h < 16; ++h) wacc[h] = make_float4(0.f, 0.f, 0.f, 0.f);
    const float* __restrict__ fb = feat + (size_t)(b * TT + t0) * FF + f;
#pragma unroll 4
    for (int t = 0; t < TC; ++t) {
        const float4 x = *reinterpret_cast<const float4*>(fb + (size_t)t * FF);
#pragma unroll
        for (int j = 0; j < 4; ++j) {
            const float4 p4 = *reinterpret_cast<const float4*>(&ls[t][j * 4]);
            wacc[j * 4 + 0].x = fmaf(p4.x, x.x, wacc[j * 4 + 0].x);
            wacc[j * 4 + 0].y = fmaf(p4.x, x.y, wacc[j * 4 + 0].y);
            wacc[j * 4 + 0].z = fmaf(p4.x, x.z, wacc[j * 4 + 0].z);
            wacc[j * 4 + 0].w = fmaf(p4.x, x.w, wacc[j * 4 + 0].w);
            wacc[j * 4 + 1].x = fmaf(p4.y, x.x, wacc[j * 4 + 1].x);
            wacc[j * 4 + 1].y = fmaf(p4.y, x.y, wacc[j * 4 + 1].y);
            wacc[j * 4 + 1].z = fmaf(p4.y, x.z, wacc[j * 4 + 1].z);
            wacc[j * 4 + 1].w = fmaf(p4.y, x.w, wacc[j * 4 + 1].w);
            wacc[j * 4 + 2].x = fmaf(p4.z, x.x, wacc[j * 4 + 2].x);
            wacc[j * 4 + 2].y = fmaf(p4.z, x.y, wacc[j * 4 + 2].y);
            wacc[j * 4 + 2].z = fmaf(p4.z, x.z, wacc[j * 4 + 2].z);
            wacc[j * 4 + 2].w = fmaf(p4.z, x.w, wacc[j * 4 + 2].w);
            wacc[j * 4 + 3].x = fmaf(p4.w, x.x, wacc[j * 4 + 3].x);
            wacc[j * 4 + 3].y = fmaf(p4.w, x.y, wacc[j * 4 + 3].y);
            wacc[j * 4 + 3].z = fmaf(p4.w, x.z, wacc[j * 4 + 3].z);
            wacc[j * 4 + 3].w = fmaf(p4.w, x.w, wacc[j * 4 + 3].w);
        }
    }
    float* __restrict__ wp = wpart + ((size_t)(b * CHUNKS + chunk) * HH) * FF + f;
#pragma unroll
    for (int h = 0; h < 16; ++h)
        *reinterpret_cast<float4*>(wp + (size_t)h * FF) = wacc[h];
}

// ---------------- combine chunk partials + pooled[b,h*64+dd] = w . Wv + bv ----------------
__global__ __launch_bounds__(256) void outkern(const float* __restrict__ wpart,
                                               const float* __restrict__ mpart,
                                               const float* __restrict__ spart,
                                               const float* __restrict__ Wv,
                                               const float* __restrict__ bv,
                                               float* __restrict__ pooled) {
    const int bh = blockIdx.x;
    const int b = bh >> 4, h = bh & 15;
    const int tid = threadIdx.x;
    __shared__ float ws_[FF];
    __shared__ float mtmp[CHUNKS], stmp[CHUNKS];
    if (tid < CHUNKS) {
        mtmp[tid] = mpart[(b * CHUNKS + tid) * HH + h];
        stmp[tid] = spart[(b * CHUNKS + tid) * HH + h];
    }
    __syncthreads();
    float M = -1e30f;
#pragma unroll
    for (int cc = 0; cc < CHUNKS; ++cc) M = fmaxf(M, mtmp[cc]);
    float Z = 0.f;
    float coef[CHUNKS];
#pragma unroll
    for (int cc = 0; cc < CHUNKS; ++cc) {
        coef[cc] = __expf(mtmp[cc] - M);
        Z = fmaf(stmp[cc], coef[cc], Z);
    }
    const float zinv = 1.f / Z;
#pragma unroll
    for (int i = 0; i < 4; ++i) {
        const int f_ = i * 256 + tid;
        float s = 0.f;
#pragma unroll 4
        for (int cc = 0; cc < CHUNKS; ++cc)
            s = fmaf(wpart[((size_t)(b * CHUNKS + cc) * HH + h) * FF + f_], coef[cc], s);
        ws_[f_] = s * zinv;
    }
    __syncthreads();
    const int dd = tid & 63;
    const int fq = tid >> 6;   // 0..3
    float acc = 0.f;
#pragma unroll 8
    for (int i = 0; i < 256; ++i) {
        const int f_ = fq * 256 + i;
        acc = fmaf(ws_[f_], Wv[(size_t)f_ * DD + h * DEPTH + dd], acc);
    }
    __shared__ float part[4][64];
    part[fq][dd] = acc;
    __syncthreads();
    if (tid < 64) {
        const float r = part[0][dd] + part[1][dd] + part[2][dd] + part[3][dd];
        pooled[b * DD + h * DEPTH + dd] = r + bv[h * DEPTH + dd];
    }
}

extern "C" void kernel_launch(void* const* d_in, const int* in_sizes, int n_in,
                              void* d_out, int out_size, void* d_ws, size_t ws_size,
                              hipStream_t stream) {
    const float* feat  = (const float*)d_in[0];
    const float* state = (const float*)d_in[1];
    const float* Wq    = (const float*)d_in[2];
    const float* bq    = (const float*)d_in[3];
    const float* Wv    = (const float*)d_in[4];
    const float* bv    = (const float*)d_in[5];
    const float* Wd    = (const float*)d_in[6];
    const float* bd    = (const float*)d_in[7];
    float* out = (float*)d_out;
    float* ws = (float*)d_ws;

    float* q      = ws;
    float* c      = ws + 32768;
    float* u      = ws + 33280;
    float* mpart  = ws + 557568;
    float* spart  = ws + 565760;
    float* wpart  = ws + 573952;
    float* pooled = ws + 8962560;

    smallgemm<<<dim3(8, BB), 256, 0, stream>>>(state, Wq, bq, q);
    ckern<<<1, 512, 0, stream>>>(q, bv, c);
    ukern<<<dim3(HH, FF / 64), 256, 0, stream>>>(Wv, q, u);
    attnfused<<<dim3(CHUNKS, BB), 256, 0, stream>>>(feat, u, c, wpart, mpart, spart);
    outkern<<<BB * HH, 256, 0, stream>>>(wpart, mpart, spart, Wv, bv, pooled);
    smallgemm<<<dim3(8, BB), 256, 0, stream>>>(pooled, Wd, bd, out);
}